// Round 8
// baseline (378.733 us; speedup 1.0000x reference)
//
#include <hip/hip_runtime.h>
#include <hip/hip_bf16.h>
#include <hip/hip_fp16.h>

typedef _Float16 f16;
typedef _Float16 f16x8 __attribute__((ext_vector_type(8)));
typedef float f32x4 __attribute__((ext_vector_type(4)));

#define SP 16384             // 128*128 spatial per batch
#define NTILES 4096          // 16-spatial tiles total (4 batches * 1024)
#define XF_BYTES ((size_t)NTILES * 40960)

// xf tile layout (40 KB per 16-spatial tile, fragment-ready):
//   byte = t*8192 + k0*1024 + c*64 + g4*16  holds x[t, d=k0*32+g4*8+e, s=tile*16+c]

__global__ void prep_weights(const float* __restrict__ Wq,
                             const float* __restrict__ Wkv,
                             const float* __restrict__ Wp,
                             f16* __restrict__ wqT,
                             f16* __restrict__ wkvT,
                             f16* __restrict__ wpT) {
  const int f = threadIdx.x;
  const int k = blockIdx.x;
  wkvT[f * 256 + k] = (f16)Wkv[k * 512 + f];
  if (f < 256) {
    wqT[f * 256 + k] = (f16)Wq[k * 256 + f];
    wpT[f * 256 + k] = (f16)Wp[k * 256 + f];
  }
}

// Kernel A: transpose/cast x -> xf (fragment layout), full input.
// blk = bl*2560 + t*512 + k0*64 + sg
__global__ __launch_bounds__(256) void xpose(const float* __restrict__ x,
                                             f16* __restrict__ xf) {
  __shared__ float ls[32 * 258];
  const int blk = blockIdx.x;
  const int sg = blk & 63;          // s-chunk of 256
  const int k0 = (blk >> 6) & 7;    // d-chunk of 32
  const int t  = (blk >> 9) % 5;
  const int bl = blk / 2560;        // batch 0..3
  const int tid = threadIdx.x;

  const float* xA = x + ((size_t)((bl * 5 + t) * 256 + k0 * 32)) * SP + sg * 256;
#pragma unroll
  for (int j = 0; j < 8; ++j) {
    const int qq = j * 256 + tid;
    const int dl = qq >> 6, s4 = qq & 63;
    const f32x4 v = *(const f32x4*)(xA + (size_t)dl * SP + s4 * 4);
    *(f32x4*)&ls[dl * 258 + s4 * 4] = v;
  }
  __syncthreads();

  const int tile_base = bl * 1024 + sg * 16;
#pragma unroll
  for (int pp = 0; pp < 4; ++pp) {
    const int piece = pp * 256 + tid;
    const int tt = piece >> 6;
    const int c  = (piece >> 2) & 15;
    const int g4 = piece & 3;
    f16x8 pk;
#pragma unroll
    for (int e = 0; e < 8; ++e)
      pk[e] = (f16)ls[(g4 * 8 + e) * 258 + tt * 16 + c];
    f16* dst = xf + (size_t)(tile_base + tt) * 20480 + t * 4096 + k0 * 512
                  + c * 32 + g4 * 8;
    *(f16x8*)dst = pk;
  }
}

// Kernel B: 1024 threads = 16 waves, wave = 1 head, 1 tile per block.
// acc = 44 f32/thread -> fits 128-reg cap -> 4 waves/SIMD (2x TLP vs R7).
// launch_bounds(1024,4): unified cap 512/4 = 128.
__global__ __launch_bounds__(1024, 4) void fused_attn(
    const f16* __restrict__ xf,
    const float* __restrict__ bq,
    const float* __restrict__ bkv,
    const float* __restrict__ bp,
    const float* __restrict__ pos_bias,
    const f16* __restrict__ wqT,
    const f16* __restrict__ wkvT,
    const f16* __restrict__ wpT,
    float* __restrict__ out) {
  __shared__ f16 fb[5 * 16 * 256];  // 40 KB fragment tile
  __shared__ f16 as_[16 * 256];     // 8 KB attn-out

  const int tid = threadIdx.x;
  const int lane = tid & 63;
  const int w = tid >> 6;    // wave 0..15 = head
  const int c = lane & 15;   // spatial index s within tile
  const int g4 = lane >> 4;  // k-group

  // ---- stage tile: 40 x gll(16B) split across 16 waves (2-3 each) ----
  {
    const char* src = (const char*)xf + (size_t)blockIdx.x * 40960 + lane * 16;
    char* dst = (char*)fb + lane * 16;
    for (int n = w; n < 40; n += 16) {
      __builtin_amdgcn_global_load_lds(
          (const void __attribute__((address_space(1)))*)(src + n * 1024),
          (void __attribute__((address_space(3)))*)(dst + n * 1024), 16, 0, 0);
    }
  }

  const f16* wqp = wqT + (w * 16 + c) * 256;
  const f16* wkp = wkvT + (w * 16 + c) * 256;
  const f16* wvp = wkvT + (256 + w * 16 + c) * 256;

  __syncthreads();  // drains gll: fb ready

  // ---- q/k/v GEMM, swapped operands: C[m=dk][n=s] ----
  f32x4 qa = {};
  f32x4 ka[5] = {};
  f32x4 va[5] = {};
  const char* fbp = (const char*)fb;
#pragma unroll 1
  for (int k0 = 0; k0 < 8; ++k0) {
    const int kk = (k0 << 5) + (g4 << 3);
    const f16x8 fq = *(const f16x8*)(wqp + kk);
    const f16x8 fk = *(const f16x8*)(wkp + kk);
    const f16x8 fv = *(const f16x8*)(wvp + kk);
    const int base = (k0 << 10) + (c << 6) + (g4 << 4);
#pragma unroll
    for (int t = 0; t < 5; ++t) {
      const f16x8 xfr = *(const f16x8*)(fbp + (t << 13) + base);
      if (t == 0) qa = __builtin_amdgcn_mfma_f32_16x16x32_f16(fq, xfr, qa, 0, 0, 0);
      ka[t] = __builtin_amdgcn_mfma_f32_16x16x32_f16(fk, xfr, ka[t], 0, 0, 0);
      va[t] = __builtin_amdgcn_mfma_f32_16x16x32_f16(fv, xfr, va[t], 0, 0, 0);
    }
  }

  // ---- per-head constants (loaded late: keeps k-loop live set small) ----
  float pb[5], bqr[4], bkr[4], bvr[4];
#pragma unroll
  for (int t = 0; t < 5; ++t) pb[t] = pos_bias[w * 5 + t];
#pragma unroll
  for (int rr = 0; rr < 4; ++rr) {
    bqr[rr] = bq[w * 16 + 4 * g4 + rr];
    bkr[rr] = bkv[w * 16 + 4 * g4 + rr];
    bvr[rr] = bkv[256 + w * 16 + 4 * g4 + rr];
  }

  // ---- attention: lane holds q/k/v[dk=4g4+rr][s=c] ----
  {
    float qv[4];
#pragma unroll
    for (int rr = 0; rr < 4; ++rr) qv[rr] = qa[rr] + bqr[rr];
    float sc[5];
#pragma unroll
    for (int t = 0; t < 5; ++t) {
      float p = 0.f;
#pragma unroll
      for (int rr = 0; rr < 4; ++rr) p += qv[rr] * (ka[t][rr] + bkr[rr]);
      p += __shfl_xor(p, 16);
      p += __shfl_xor(p, 32);
      sc[t] = p * 4.0f + pb[t];  // /temperature (=0.25) + pos_bias
    }
    float m = sc[0];
#pragma unroll
    for (int t = 1; t < 5; ++t) m = fmaxf(m, sc[t]);
    float l = 0.f;
#pragma unroll
    for (int t = 0; t < 5; ++t) { sc[t] = __expf(sc[t] - m); l += sc[t]; }
    const float inv = 1.0f / l;
    float oo[4];
#pragma unroll
    for (int rr = 0; rr < 4; ++rr) {
      float o = 0.f;
#pragma unroll
      for (int t = 0; t < 5; ++t) o += sc[t] * (va[t][rr] + bvr[rr]);
      oo[rr] = o * inv;
    }
#pragma unroll
    for (int pr = 0; pr < 2; ++pr) {
      const int feat0 = w * 16 + 4 * g4 + 2 * pr;
      const int byte = ((feat0 >> 5) << 10) + (c << 6) +
                       ((((feat0 >> 3) & 3) ^ (c & 3)) << 4) + ((feat0 & 7) << 1);
      union { f16 hh[2]; unsigned uu; } pk;
      pk.hh[0] = (f16)oo[0 + 2 * pr];
      pk.hh[1] = (f16)oo[1 + 2 * pr];
      *(unsigned*)((char*)as_ + byte) = pk.uu;
    }
  }
  __syncthreads();  // as_ visible

  // ---- projection: attn_out[16s x 256] @ Wp -> C[m=s][n=w*16+c] ----
  const f16* wpp = wpT + (w * 16 + c) * 256;
  f32x4 fa = {};
#pragma unroll 1
  for (int k0 = 0; k0 < 8; ++k0) {
    const int kk = (k0 << 5) + (g4 << 3);
    const f16x8 af = *(const f16x8*)((const char*)as_ + (k0 << 10) + (c << 6) +
                                     ((g4 ^ (c & 3)) << 4));
    const f16x8 f0 = *(const f16x8*)(wpp + kk);
    fa = __builtin_amdgcn_mfma_f32_16x16x32_f16(af, f0, fa, 0, 0, 0);
  }

  // ---- store: out[b, w*16+c, s0 + 4*g4 + rr] ----
  {
    const int g = blockIdx.x;
    const int b = g >> 10, s0 = (g & 1023) << 4;
    const int dg = w * 16 + c;
    const float bias = bp[dg];
    f32x4 vs = fa;
#pragma unroll
    for (int rr = 0; rr < 4; ++rr) vs[rr] += bias;
    float* dst = out + ((size_t)b * 256 + dg) * SP + s0 + (g4 << 2);
    *(f32x4*)dst = vs;
  }
}

extern "C" void kernel_launch(void* const* d_in, const int* in_sizes, int n_in,
                              void* d_out, int out_size, void* d_ws, size_t ws_size,
                              hipStream_t stream) {
  const float* x   = (const float*)d_in[0];
  const float* Wq  = (const float*)d_in[1];
  const float* bq  = (const float*)d_in[2];
  const float* Wkv = (const float*)d_in[3];
  const float* bkv = (const float*)d_in[4];
  const float* Wp  = (const float*)d_in[5];
  const float* bp  = (const float*)d_in[6];
  const float* pos = (const float*)d_in[7];

  f16* xf   = (f16*)d_ws;                      // 168 MB (L3-resident)
  f16* wqT  = (f16*)((char*)d_ws + XF_BYTES);
  f16* wkvT = wqT + 256 * 256;
  f16* wpT  = wkvT + 512 * 256;

  prep_weights<<<256, 512, 0, stream>>>(Wq, Wkv, Wp, wqT, wkvT, wpT);
  xpose<<<10240, 256, 0, stream>>>(x, xf);
  fused_attn<<<NTILES, 1024, 0, stream>>>(xf, bq, bkv, bp, pos,
                                          wqT, wkvT, wpT, (float*)d_out);
}

// Round 9
// 297.559 us; speedup vs baseline: 1.2728x; 1.2728x over previous
//
#include <hip/hip_runtime.h>
#include <hip/hip_bf16.h>
#include <hip/hip_fp16.h>

typedef _Float16 f16;
typedef _Float16 f16x8 __attribute__((ext_vector_type(8)));
typedef float f32x4 __attribute__((ext_vector_type(4)));

#define SP 16384             // 128*128 spatial per batch
#define NTILES 4096          // 16-spatial tiles total (4 batches * 1024)
#define XF_BYTES ((size_t)NTILES * 40960)

// xf tile layout (40 KB per 16-spatial tile, fragment-ready, LANE-LINEAR):
//   byte = t*8192 + k0*1024 + g4*256 + c*16 + e*2
//   holds x[t, d=k0*32+g4*8+e, s=tile*16+c]
// A wave's b128 fragment read (lane = g4*16+c -> byte g4*256+c*16) is a
// contiguous 1024B block: conflict-free by construction. (R8's c*64+g4*16
// layout collapsed onto banks {0,16}: 8-way conflict, 13.4M cycles.)

__global__ void prep_weights(const float* __restrict__ Wq,
                             const float* __restrict__ Wkv,
                             const float* __restrict__ Wp,
                             f16* __restrict__ wqT,
                             f16* __restrict__ wkvT,
                             f16* __restrict__ wpT) {
  const int f = threadIdx.x;
  const int k = blockIdx.x;
  wkvT[f * 256 + k] = (f16)Wkv[k * 512 + f];
  if (f < 256) {
    wqT[f * 256 + k] = (f16)Wq[k * 256 + f];
    wpT[f * 256 + k] = (f16)Wp[k * 256 + f];
  }
}

// Kernel A: transpose/cast x -> xf (fragment layout), full input.
__global__ __launch_bounds__(256) void xpose(const float* __restrict__ x,
                                             f16* __restrict__ xf) {
  __shared__ float ls[32 * 258];
  const int blk = blockIdx.x;
  const int sg = blk & 63;          // s-chunk of 256
  const int k0 = (blk >> 6) & 7;    // d-chunk of 32
  const int t  = (blk >> 9) % 5;
  const int bl = blk / 2560;        // batch 0..3
  const int tid = threadIdx.x;

  const float* xA = x + ((size_t)((bl * 5 + t) * 256 + k0 * 32)) * SP + sg * 256;
#pragma unroll
  for (int j = 0; j < 8; ++j) {
    const int qq = j * 256 + tid;
    const int dl = qq >> 6, s4 = qq & 63;
    const f32x4 v = *(const f32x4*)(xA + (size_t)dl * SP + s4 * 4);
    *(f32x4*)&ls[dl * 258 + s4 * 4] = v;
  }
  __syncthreads();

  const int tile_base = bl * 1024 + sg * 16;
#pragma unroll
  for (int pp = 0; pp < 4; ++pp) {
    const int piece = pp * 256 + tid;
    const int tt = piece >> 6;
    const int c  = (piece >> 2) & 15;
    const int g4 = piece & 3;
    f16x8 pk;
#pragma unroll
    for (int e = 0; e < 8; ++e)
      pk[e] = (f16)ls[(g4 * 8 + e) * 258 + tt * 16 + c];
    // lane-linear layout: f16 index = t*4096 + k0*512 + g4*128 + c*8
    f16* dst = xf + (size_t)(tile_base + tt) * 20480 + t * 4096 + k0 * 512
                  + g4 * 128 + c * 8;
    *(f16x8*)dst = pk;
  }
}

// Kernel B: 2 tiles (32 spatial) per block; tile-loop inside each k-step so
// one weight-fragment load feeds 2x the MFMA work. launch_bounds(512,2):
// 256-reg unified cap (acc=176 + frags fits; NEVER more than 2 waves/EU).
__global__ __launch_bounds__(512, 2) void fused_attn(
    const f16* __restrict__ xf,
    const float* __restrict__ bq,
    const float* __restrict__ bkv,
    const float* __restrict__ bp,
    const float* __restrict__ pos_bias,
    const f16* __restrict__ wqT,
    const f16* __restrict__ wkvT,
    const f16* __restrict__ wpT,
    float* __restrict__ out) {
  __shared__ f16 fb[2 * 5 * 16 * 256];  // 2 x 40 KB fragment tiles
  __shared__ f16 as_[2 * 16 * 256];     // 2 x 8 KB attn-out (lane-linear)

  const int tid = threadIdx.x;
  const int lane = tid & 63;
  const int w = tid >> 6;    // wave 0..7 -> heads 2w, 2w+1
  const int c = lane & 15;
  const int g4 = lane >> 4;
  const int hA = 2 * w;

  const int g0 = blockIdx.x * 2;  // tiles g0, g0+1

  // ---- stage both tiles: 20 x global_load_lds(16B) per wave ----
#pragma unroll
  for (int u = 0; u < 2; ++u) {
    const char* src = (const char*)xf + ((size_t)blockIdx.x * 2 + u) * 40960
                      + w * 5120 + lane * 16;
    char* dst = (char*)fb + u * 40960 + w * 5120 + lane * 16;
#pragma unroll
    for (int n = 0; n < 10; ++n) {
      __builtin_amdgcn_global_load_lds(
          (const void __attribute__((address_space(1)))*)(src + n * 512),
          (void __attribute__((address_space(3)))*)(dst + n * 512), 16, 0, 0);
    }
  }

  // ---- hoisted per-lane constants ----
  float pb[2][5], bpv[2], bqr[2][4], bkr[2][4], bvr[2][4];
#pragma unroll
  for (int j = 0; j < 2; ++j) {
    const int hj = hA + j;
    bpv[j] = bp[hj * 16 + c];
#pragma unroll
    for (int t = 0; t < 5; ++t) pb[j][t] = pos_bias[hj * 5 + t];
#pragma unroll
    for (int rr = 0; rr < 4; ++rr) {
      bqr[j][rr] = bq[hj * 16 + 4 * g4 + rr];
      bkr[j][rr] = bkv[hj * 16 + 4 * g4 + rr];
      bvr[j][rr] = bkv[256 + hj * 16 + 4 * g4 + rr];
    }
  }
  const f16* wqp0 = wqT + (hA * 16 + c) * 256;
  const f16* wqp1 = wqT + ((hA + 1) * 16 + c) * 256;
  const f16* wkp0 = wkvT + (hA * 16 + c) * 256;
  const f16* wkp1 = wkvT + ((hA + 1) * 16 + c) * 256;
  const f16* wvp0 = wkvT + (256 + hA * 16 + c) * 256;
  const f16* wvp1 = wkvT + (256 + (hA + 1) * 16 + c) * 256;
  const f16* wpp0 = wpT + (hA * 16 + c) * 256;
  const f16* wpp1 = wpT + ((hA + 1) * 16 + c) * 256;

  __syncthreads();  // drains gll: fb ready

  // ---- q/k/v GEMM: one weight-frag set per k0 feeds both tiles ----
  f32x4 qacc[2][2] = {};      // [tile][head]
  f32x4 kacc[2][2][5] = {};
  f32x4 vacc[2][2][5] = {};
#pragma unroll 1
  for (int k0 = 0; k0 < 8; ++k0) {
    const int kk = (k0 << 5) + (g4 << 3);
    const f16x8 fq0 = *(const f16x8*)(wqp0 + kk);
    const f16x8 fq1 = *(const f16x8*)(wqp1 + kk);
    const f16x8 fk0 = *(const f16x8*)(wkp0 + kk);
    const f16x8 fk1 = *(const f16x8*)(wkp1 + kk);
    const f16x8 fv0 = *(const f16x8*)(wvp0 + kk);
    const f16x8 fv1 = *(const f16x8*)(wvp1 + kk);
    const int base = (k0 << 10) + (g4 << 8) + (c << 4);  // lane-linear
#pragma unroll
    for (int u = 0; u < 2; ++u) {
      const char* fbp = (const char*)fb + u * 40960;
      f16x8 xfr[5];
#pragma unroll
      for (int t = 0; t < 5; ++t) xfr[t] = *(const f16x8*)(fbp + (t << 13) + base);

      qacc[u][0] = __builtin_amdgcn_mfma_f32_16x16x32_f16(fq0, xfr[0], qacc[u][0], 0, 0, 0);
      qacc[u][1] = __builtin_amdgcn_mfma_f32_16x16x32_f16(fq1, xfr[0], qacc[u][1], 0, 0, 0);
#pragma unroll
      for (int t = 0; t < 5; ++t) {
        kacc[u][0][t] = __builtin_amdgcn_mfma_f32_16x16x32_f16(fk0, xfr[t], kacc[u][0][t], 0, 0, 0);
        kacc[u][1][t] = __builtin_amdgcn_mfma_f32_16x16x32_f16(fk1, xfr[t], kacc[u][1][t], 0, 0, 0);
        vacc[u][0][t] = __builtin_amdgcn_mfma_f32_16x16x32_f16(fv0, xfr[t], vacc[u][0][t], 0, 0, 0);
        vacc[u][1][t] = __builtin_amdgcn_mfma_f32_16x16x32_f16(fv1, xfr[t], vacc[u][1][t], 0, 0, 0);
      }
    }
  }

  // ---- attention per tile (lane holds q/k/v[dk=4g4+rr][s=c]) ----
#pragma unroll
  for (int u = 0; u < 2; ++u) {
#pragma unroll
    for (int j = 0; j < 2; ++j) {
      float qv[4];
#pragma unroll
      for (int rr = 0; rr < 4; ++rr) qv[rr] = qacc[u][j][rr] + bqr[j][rr];
      float sc[5];
#pragma unroll
      for (int t = 0; t < 5; ++t) {
        float p = 0.f;
#pragma unroll
        for (int rr = 0; rr < 4; ++rr) p += qv[rr] * (kacc[u][j][t][rr] + bkr[j][rr]);
        p += __shfl_xor(p, 16);
        p += __shfl_xor(p, 32);
        sc[t] = p * 4.0f + pb[j][t];  // /temperature (=0.25) + pos_bias
      }
      float m = sc[0];
#pragma unroll
      for (int t = 1; t < 5; ++t) m = fmaxf(m, sc[t]);
      float l = 0.f;
#pragma unroll
      for (int t = 0; t < 5; ++t) { sc[t] = __expf(sc[t] - m); l += sc[t]; }
      const float inv = 1.0f / l;
      // attn_out[feat = (2w+j)*16+4g4+rr][s=c] -> one aligned b64 write:
      // byte = w*1024 + (2j+(g4>>1))*256 + c*16 + (g4&1)*8   (2-way max)
      union { f16 hh[4]; unsigned long long uu; } pk;
#pragma unroll
      for (int rr = 0; rr < 4; ++rr) {
        float o = 0.f;
#pragma unroll
        for (int t = 0; t < 5; ++t) o += sc[t] * (vacc[u][j][t][rr] + bvr[j][rr]);
        pk.hh[rr] = (f16)(o * inv);
      }
      const int byte = (w << 10) + ((2 * j + (g4 >> 1)) << 8) + (c << 4)
                       + ((g4 & 1) << 3);
      *(unsigned long long*)((char*)as_ + u * 8192 + byte) = pk.uu;
    }
  }
  __syncthreads();  // as_ visible

  // ---- projection: one wp-frag set per k0 feeds both tiles ----
  f32x4 facc[2][2] = {};
#pragma unroll 1
  for (int k0 = 0; k0 < 8; ++k0) {
    const int kk = (k0 << 5) + (g4 << 3);
    const f16x8 f0 = *(const f16x8*)(wpp0 + kk);
    const f16x8 f1 = *(const f16x8*)(wpp1 + kk);
    const int abyte = (k0 << 10) + (g4 << 8) + (c << 4);  // lane-linear
#pragma unroll
    for (int u = 0; u < 2; ++u) {
      const f16x8 af = *(const f16x8*)((const char*)as_ + u * 8192 + abyte);
      facc[u][0] = __builtin_amdgcn_mfma_f32_16x16x32_f16(af, f0, facc[u][0], 0, 0, 0);
      facc[u][1] = __builtin_amdgcn_mfma_f32_16x16x32_f16(af, f1, facc[u][1], 0, 0, 0);
    }
  }

  // ---- store ----
#pragma unroll
  for (int u = 0; u < 2; ++u) {
    const int g = g0 + u;
    const int b = g >> 10, s0 = (g & 1023) << 4;
#pragma unroll
    for (int j = 0; j < 2; ++j) {
      const int dg = (hA + j) * 16 + c;
      f32x4 vs = facc[u][j];
#pragma unroll
      for (int rr = 0; rr < 4; ++rr) vs[rr] += bpv[j];
      float* dst = out + ((size_t)b * 256 + dg) * SP + s0 + (g4 << 2);
      *(f32x4*)dst = vs;
    }
  }
}

extern "C" void kernel_launch(void* const* d_in, const int* in_sizes, int n_in,
                              void* d_out, int out_size, void* d_ws, size_t ws_size,
                              hipStream_t stream) {
  const float* x   = (const float*)d_in[0];
  const float* Wq  = (const float*)d_in[1];
  const float* bq  = (const float*)d_in[2];
  const float* Wkv = (const float*)d_in[3];
  const float* bkv = (const float*)d_in[4];
  const float* Wp  = (const float*)d_in[5];
  const float* bp  = (const float*)d_in[6];
  const float* pos = (const float*)d_in[7];

  f16* xf   = (f16*)d_ws;                      // 168 MB
  f16* wqT  = (f16*)((char*)d_ws + XF_BYTES);
  f16* wkvT = wqT + 256 * 256;
  f16* wpT  = wkvT + 512 * 256;

  prep_weights<<<256, 512, 0, stream>>>(Wq, Wkv, Wp, wqT, wkvT, wpT);
  xpose<<<10240, 256, 0, stream>>>(x, xf);
  fused_attn<<<NTILES / 2, 512, 0, stream>>>(xf, bq, bkv, bp, pos,
                                             wqT, wkvT, wpT, (float*)d_out);
}